// Round 13
// baseline (329.187 us; speedup 1.0000x reference)
//
#include <hip/hip_runtime.h>
#include <hip/hip_bf16.h>
#include <stdint.h>

typedef __attribute__((ext_vector_type(8))) short short8;
typedef __attribute__((ext_vector_type(4))) float f32x4;

#define M_DIM 8192
#define N_DIM 4096
#define K_DIM 4096
#define BM 256
#define BN 128
#define BK 32

static __device__ __forceinline__ unsigned short f32_to_bf16(float f) {
  union { float f; unsigned int u; } v; v.f = f;
  unsigned int u = v.u;
  u += 0x7fffu + ((u >> 16) & 1u);   // round-to-nearest-even
  return (unsigned short)(u >> 16);
}

// ------- fused prep: blocks [0,16384) cast x->bf16; [16384,18432) dequant ----
// (validated R9/R11)
__global__ void prep_kernel(const float* __restrict__ x,
                            unsigned short* __restrict__ xb,
                            const int* __restrict__ qw,
                            const float* __restrict__ scale,
                            const float* __restrict__ zero,
                            unsigned short* __restrict__ W) {
  if (blockIdx.x < 16384) {
    size_t i = ((size_t)blockIdx.x * blockDim.x + threadIdx.x) * 8;
    float4 v0 = *reinterpret_cast<const float4*>(x + i);
    float4 v1 = *reinterpret_cast<const float4*>(x + i + 4);
    short8 o;
    o[0] = (short)f32_to_bf16(v0.x);
    o[1] = (short)f32_to_bf16(v0.y);
    o[2] = (short)f32_to_bf16(v0.z);
    o[3] = (short)f32_to_bf16(v0.w);
    o[4] = (short)f32_to_bf16(v1.x);
    o[5] = (short)f32_to_bf16(v1.y);
    o[6] = (short)f32_to_bf16(v1.z);
    o[7] = (short)f32_to_bf16(v1.w);
    *reinterpret_cast<short8*>(xb + i) = o;
  } else {
    int idx = (blockIdx.x - 16384) * blockDim.x + threadIdx.x;   // n*128 + c
    int n = idx >> 7;
    int c = idx & 127;
    unsigned int w[8];
#pragma unroll
    for (int k = 0; k < 8; ++k)
      w[k] = (unsigned int)qw[(size_t)k * (N_DIM * 128) + idx];
    int wp = c >> 5, t = c & 31;
#pragma unroll
    for (int s = 0; s < 4; ++s) {
      int r = s ^ 3;
      unsigned int by[8];
#pragma unroll
      for (int k = 0; k < 8; ++k) by[k] = (w[k] >> (8 * r)) & 0xffu;
      int ibase = wp * 1024 + s * 256 + t * 8;
      int g = ibase >> 7;
      float sc = scale[n * 32 + g];
      float zp = zero[n * 32 + g] * 16.0f;
      short8 o;
#pragma unroll
      for (int u = 0; u < 8; ++u) {
        unsigned int q = 0;
#pragma unroll
        for (int k = 0; k < 8; ++k)
          q |= ((by[k] >> (7 - u)) & 1u) << (7 - k);
        o[u] = (short)f32_to_bf16(sc * ((float)q - zp));
      }
      *reinterpret_cast<short8*>(&W[(size_t)n * K_DIM + ibase]) = o;
    }
  }
}

// ---- 256x128 tile, BK=32, 3-buffer, 2 blocks/CU (R13 = R12 + drain fix) ----
// C[M][N] = A[M][K] * B[N][K]^T + bias. 8 waves (4M x 2N), wave out 64x64.
// Region r (kt=r): SB0; prio1; 8 ds_reads (buf r%3); 3 stages (kt+2 ->
// buf (r+2)%3); 16 MFMA; prio0; vmcnt(3); SB0; barrier.
// R12 NaN post-mortem: R12 did barrier -> drain -> read in ONE region, so
// wave A read wave B's slots with no barrier after B's drain (vmcnt is
// per-wave). FIX: drain moved to region END, before the exit barrier:
//   stage(s) -> every wave drains it at end of s+1 (vmcnt(3): outstanding
//   stage(s)+stage(s+1)=6 -> 3) -> s+2 entry barrier -> read at s+2. ✓
// Prologue: stage kt0,kt1; vmcnt(3) drains kt0; SB0; barrier; region 0
// reads kt0 (drain->barrier->read ✓, R5 lesson). Peel: r126 ends vmcnt(0)
// (drains kt127, staged r125); r127 reads it post-barrier.
// Overwrite: buf[(r+2)%3] re-staged at r; its old data (kt r-1) was last
// read at r-1, reads complete before r-1's MFMAs (lgkm) -> before r-1's
// exit barrier -> stage issued after that barrier ✓.
// Occupancy thesis (m114): 72KB LDS + <=128 regs -> 2 blocks/CU; the
// co-resident block's MFMAs hide this block's barrier/read-latency stalls.
// Swizzle (64B rows): read byte ^= ((row>>1)&3)<<4; stage SOURCE slot
// ^= ((tid>>3)&3) (both-sides, rule #21). Group-of-8 lane bank-slot
// coverage verified distinct (conflict-free).

#define VMCNT3 asm volatile("s_waitcnt vmcnt(3)" ::: "memory")
#define VMCNT0 asm volatile("s_waitcnt vmcnt(0)" ::: "memory")
#define NOOP ((void)0)
#define SB0 __builtin_amdgcn_sched_barrier(0)

#define STG_CALL(G, GROWB, KT, LDSC)                                           \
  __builtin_amdgcn_global_load_lds(                                            \
      (const __attribute__((address_space(1))) void*)                          \
          ((G) + ((size_t)(GROWB) * K_DIM + (KT) * 32 + s_off)),               \
      (__attribute__((address_space(3))) void*)(smem + (LDSC) + wslot),        \
      16, 0, 0)

// stage K-tile KT2 into buffer QS: A rows [0,128),[128,256), B rows [0,128)
#define STAGE3(QS, KT2) do {                                                   \
  STG_CALL(Ag, m0,       (KT2), 24576 + (QS) * 16384);                         \
  STG_CALL(Ag, m0 + 128, (KT2), 24576 + (QS) * 16384 + 8192);                  \
  STG_CALL(Bg, n0,       (KT2), (QS) * 8192);                                  \
} while (0)

#define RD16(IMM, OFF) (*(const short8*)(smem + (OFF) + (IMM)))
// this region's operands: 4 A-frags + 4 B-frags, interleaved
#define LRD(Q) do {                                                            \
  a_[0] = RD16(24576 + (Q) * 16384,        a_off);                             \
  b_[0] = RD16((Q) * 8192,                 b_off);                             \
  a_[1] = RD16(24576 + (Q) * 16384 + 1024, a_off);                             \
  b_[1] = RD16((Q) * 8192 + 1024,          b_off);                             \
  a_[2] = RD16(24576 + (Q) * 16384 + 2048, a_off);                             \
  b_[2] = RD16((Q) * 8192 + 2048,          b_off);                             \
  a_[3] = RD16(24576 + (Q) * 16384 + 3072, a_off);                             \
  b_[3] = RD16((Q) * 8192 + 3072,          b_off);                             \
} while (0)

#define MFMA16()                                                               \
  _Pragma("unroll") for (int mf_ = 0; mf_ < 4; ++mf_)                          \
    _Pragma("unroll") for (int nf_ = 0; nf_ < 4; ++nf_)                        \
      acc[mf_][nf_] = __builtin_amdgcn_mfma_f32_16x16x32_bf16(                 \
          a_[mf_], b_[nf_], acc[mf_][nf_], 0, 0, 0)

// region: SB0; prio1; reads; stage; MFMA; prio0; WAITV; SB0; barrier.
// Entry SB0 + prior region's asm-memory-clobber pin ds_reads AFTER the
// preceding barrier (rule #18 family).
#define REGION(Q, STAGE, WAITV) do {                                           \
  SB0;                                                                         \
  __builtin_amdgcn_s_setprio(1);                                               \
  LRD(Q);                                                                      \
  STAGE;                                                                       \
  MFMA16();                                                                    \
  __builtin_amdgcn_s_setprio(0);                                               \
  WAITV;                                                                       \
  SB0;                                                                         \
  __builtin_amdgcn_s_barrier();                                                \
} while (0)

__global__ __launch_bounds__(512, 4) void gemm_kernel(
    const unsigned short* __restrict__ Ag,   // Xb [M][K] bf16
    const unsigned short* __restrict__ Bg,   // Wb [N][K] bf16
    const float* __restrict__ bias,
    float* __restrict__ C) {
  __shared__ __align__(16) char smem[73728];   // B: 3x8KB @0, A: 3x16KB @24576

  // XCD-aware bijective swizzle: 1024 blocks % 8 == 0
  int bid = blockIdx.x;
  int cpx = gridDim.x >> 3;
  int swz = (bid & 7) * cpx + (bid >> 3);
  int tm = swz >> 5;                 // 32 M-tiles
  int tn = swz & 31;                 // 32 N-tiles (consecutive swz share A-panel)
  int m0 = tm * BM, n0 = tn * BN;

  int tid = threadIdx.x;
  int lane = tid & 63;
  int wid = tid >> 6;                // 8 waves
  int wm = wid >> 1, wn = wid & 1;   // 4 x 2

  // read addressing: row stride 64B; swizzle XOR ((row>>1)&3)<<4
  const int arow = wm * 64 + (lane & 15);      // + mf*16 rows (mf*1024 B imm)
  const int bcol = wn * 64 + (lane & 15);      // + nf*16 rows
  const int slot4 = (lane >> 4) << 4;          // k-slot byte offset
  const int a_off = (arow << 6) + (slot4 ^ (((arow >> 1) & 3) << 4));
  const int b_off = (bcol << 6) + (slot4 ^ (((bcol >> 1) & 3) << 4));
  // stage addressing: linear dest (wave slot + lane*16), inverse-swizzled src
  const int wslot = wid << 10;
  const int s_row = tid >> 2;                  // 4 threads per 64B row
  const int s_off = s_row * K_DIM + (((tid & 3) ^ ((tid >> 3) & 3)) << 3);

  short8 a_[4], b_[4];
  f32x4 acc[4][4];
#pragma unroll
  for (int mf = 0; mf < 4; ++mf)
#pragma unroll
    for (int nf = 0; nf < 4; ++nf) acc[mf][nf] = (f32x4){0.f, 0.f, 0.f, 0.f};

  // prologue: stage kt0 -> buf0, kt1 -> buf1; drain kt0 (vmcnt(3) leaves
  // kt1's 3 in flight); SB0; barrier -> every wave's kt0 drain precedes the
  // barrier, so region 0's cross-slot reads are safe (drain->barrier->read).
  STAGE3(0, 0);
  STAGE3(1, 1);
  VMCNT3;
  SB0;
  __builtin_amdgcn_s_barrier();

  for (int t = 0; t < 42; ++t) {
    const int kt = 3 * t;
    REGION(0, STAGE3(2, kt + 2), VMCNT3);
    REGION(1, STAGE3(0, kt + 3), VMCNT3);
    REGION(2, STAGE3(1, kt + 4), VMCNT3);
  }
  REGION(0, NOOP, VMCNT0);   // kt=126; end-drain kt127 (staged r125)
  REGION(1, NOOP, NOOP);     // kt=127

  // epilogue: C/D layout col=lane&15, row=(lane>>4)*4+j
#pragma unroll
  for (int nf = 0; nf < 4; ++nf) {
    int gcol = n0 + wn * 64 + nf * 16 + (lane & 15);
    float bv = bias[gcol];
#pragma unroll
    for (int mf = 0; mf < 4; ++mf) {
      int grow = m0 + wm * 64 + mf * 16 + ((lane >> 4) << 2);
      f32x4 v = acc[mf][nf];
#pragma unroll
      for (int j = 0; j < 4; ++j)
        C[(size_t)(grow + j) * N_DIM + gcol] = v[j] + bv;
    }
  }
}

extern "C" void kernel_launch(void* const* d_in, const int* in_sizes, int n_in,
                              void* d_out, int out_size, void* d_ws, size_t ws_size,
                              hipStream_t stream) {
  const float* x       = (const float*)d_in[0];
  const int*   qweight = (const int*)d_in[1];
  const float* scale   = (const float*)d_in[2];
  const float* zero    = (const float*)d_in[3];
  const float* bias    = (const float*)d_in[4];
  float* out = (float*)d_out;

  unsigned short* Xb = (unsigned short*)d_ws;                    // 64 MB
  unsigned short* Wb = Xb + (size_t)M_DIM * K_DIM;               // 32 MB

  prep_kernel<<<16384 + 2048, 256, 0, stream>>>(x, Xb, qweight, scale, zero, Wb);
  gemm_kernel<<<(M_DIM / BM) * (N_DIM / BN), 512, 0, stream>>>(Xb, Wb, bias, out);
}

// Round 14
// 259.521 us; speedup vs baseline: 1.2684x; 1.2684x over previous
//
#include <hip/hip_runtime.h>
#include <hip/hip_bf16.h>
#include <stdint.h>

typedef __attribute__((ext_vector_type(8))) short short8;
typedef __attribute__((ext_vector_type(4))) float f32x4;

#define M_DIM 8192
#define N_DIM 4096
#define K_DIM 4096
#define BM 256
#define BN 256
#define BK 64

static __device__ __forceinline__ unsigned short f32_to_bf16(float f) {
  union { float f; unsigned int u; } v; v.f = f;
  unsigned int u = v.u;
  u += 0x7fffu + ((u >> 16) & 1u);   // round-to-nearest-even
  return (unsigned short)(u >> 16);
}

// ------- fused prep: blocks [0,16384) cast x->bf16; [16384,18432) dequant ----
// (validated R9/R11; ~43us, near the 38us HBM floor for 240MB of traffic)
__global__ void prep_kernel(const float* __restrict__ x,
                            unsigned short* __restrict__ xb,
                            const int* __restrict__ qw,
                            const float* __restrict__ scale,
                            const float* __restrict__ zero,
                            unsigned short* __restrict__ W) {
  if (blockIdx.x < 16384) {
    size_t i = ((size_t)blockIdx.x * blockDim.x + threadIdx.x) * 8;
    float4 v0 = *reinterpret_cast<const float4*>(x + i);
    float4 v1 = *reinterpret_cast<const float4*>(x + i + 4);
    short8 o;
    o[0] = (short)f32_to_bf16(v0.x);
    o[1] = (short)f32_to_bf16(v0.y);
    o[2] = (short)f32_to_bf16(v0.z);
    o[3] = (short)f32_to_bf16(v0.w);
    o[4] = (short)f32_to_bf16(v1.x);
    o[5] = (short)f32_to_bf16(v1.y);
    o[6] = (short)f32_to_bf16(v1.z);
    o[7] = (short)f32_to_bf16(v1.w);
    *reinterpret_cast<short8*>(xb + i) = o;
  } else {
    int idx = (blockIdx.x - 16384) * blockDim.x + threadIdx.x;   // n*128 + c
    int n = idx >> 7;
    int c = idx & 127;
    unsigned int w[8];
#pragma unroll
    for (int k = 0; k < 8; ++k)
      w[k] = (unsigned int)qw[(size_t)k * (N_DIM * 128) + idx];
    int wp = c >> 5, t = c & 31;
#pragma unroll
    for (int s = 0; s < 4; ++s) {
      int r = s ^ 3;
      unsigned int by[8];
#pragma unroll
      for (int k = 0; k < 8; ++k) by[k] = (w[k] >> (8 * r)) & 0xffu;
      int ibase = wp * 1024 + s * 256 + t * 8;
      int g = ibase >> 7;
      float sc = scale[n * 32 + g];
      float zp = zero[n * 32 + g] * 16.0f;
      short8 o;
#pragma unroll
      for (int u = 0; u < 8; ++u) {
        unsigned int q = 0;
#pragma unroll
        for (int k = 0; k < 8; ++k)
          q |= ((by[k] >> (7 - u)) & 1u) << (7 - k);
        o[u] = (short)f32_to_bf16(sc * ((float)q - zp));
      }
      *reinterpret_cast<short8*>(&W[(size_t)n * K_DIM + ibase]) = o;
    }
  }
}

// ---- 256x256 8-region bf16 GEMM — byte-exact R8/R11 (verified: 214us GEMM,
// MfmaUtil 61%, 0 bank conflicts, absmax 1.0; matrix-busy ~= 132us MFMA floor) ----
// C[M][N] = A[M][K] * B[N][K]^T + bias. 8 waves (2Mx4N), wave out 128x64.
// Region p: bar; vmcnt(2); SB0; prio1; stage; kk0-MFMA(8); rd(p+1,kk0); SB0;
//           kk1-MFMA(8); rd(p+1,kk1); SB0; prio0.
// No explicit lgkmcnt(0) at entry — compiler emits precise counted lgkm
// waits before each consuming MFMA octet. Cross-wave visibility ledger:
// pair staged at region s -> all-waves drain (vmcnt after barrier) at
// s+1..s+2 entry -> read at >= s+3 (drain->barrier->read on every edge).
// Prologue drains buf0 (vmcnt(2)) + barrier BEFORE any cross-slot ds_read
// (R5 NaN lesson). Peel pulls the A(1,1,63) drain to p5 (vmcnt(0)).
// Structure-space notes from this session (all verified on HW):
//  - R7 full reg-pingpong: -9% (read burst at barrier exit beats MFMA start)
//  - R9 quad-interleave: -3% (SB0 fence overhead > smoother port issue)
//  - R10 mfma 32x32x16: +2.9e7 bank conflicts (mechanism unexplained), -9%
//  - R13 256x128/BK=32/2-blocks-per-CU: MfmaUtil 42%, -38% (no prefetch
//    possible with 3-buf stage-ahead-2; 1.5x global traffic)

#define VMCNT2 asm volatile("s_waitcnt vmcnt(2)" ::: "memory")
#define VMCNT0 asm volatile("s_waitcnt vmcnt(0)" ::: "memory")
#define NOOP ((void)0)
#define SB0 __builtin_amdgcn_sched_barrier(0)

#define STG(G, GROWB, KT, LDSC) do {                                           \
  const unsigned short* sb_ = (G) + ((size_t)(GROWB) * K_DIM + (KT) * 64);     \
  __builtin_amdgcn_global_load_lds(                                            \
      (const __attribute__((address_space(1))) void*)(sb_ + s_off0),           \
      (__attribute__((address_space(3))) void*)(smem + (LDSC) + wslot),        \
      16, 0, 0);                                                               \
  __builtin_amdgcn_global_load_lds(                                            \
      (const __attribute__((address_space(1))) void*)(sb_ + s_off1),           \
      (__attribute__((address_space(3))) void*)(smem + (LDSC) + 8192 + wslot), \
      16, 0, 0);                                                               \
} while (0)
#define STG_A(BUF, H, KT) STG(Ag, m0 + (H)*128, (KT), ((BUF)*2 + (H)) * 16384)
#define STG_B(BUF, H, KT) STG(Bg, n0 + (H)*128, (KT), 65536 + ((BUF)*2 + (H)) * 16384)

// reads for ONE k-slot (KK literal): 4 A-frags or 2 B-frags
#define LA(BUF, QM, KK) do {                                                   \
  _Pragma("unroll") for (int mf_ = 0; mf_ < 4; ++mf_)                          \
    a_[mf_][KK] = *(const short8*)(smem + ((KK) ? a_off1 : a_off0) +           \
        (((BUF)*2 + (QM)) * 16384 + mf_ * 2048));                              \
} while (0)
#define LB(BUF, QN, KK) do {                                                   \
  _Pragma("unroll") for (int nf_ = 0; nf_ < 2; ++nf_)                          \
    b_[nf_][KK] = *(const short8*)(smem + ((KK) ? b_off1 : b_off0) +           \
        (((BUF)*2 + (QN)) * 16384 + nf_ * 2048));                              \
} while (0)

#define MFMA_KK(QM, QN, KK)                                                    \
  _Pragma("unroll") for (int mf_ = 0; mf_ < 4; ++mf_)                          \
    _Pragma("unroll") for (int nf_ = 0; nf_ < 2; ++nf_)                        \
      acc[QM][QN][mf_][nf_] = __builtin_amdgcn_mfma_f32_16x16x32_bf16(         \
          a_[mf_][KK], b_[nf_][KK], acc[QM][QN][mf_][nf_], 0, 0, 0)

// one region; RD0/RD1 load operands for the NEXT region's MFMAs.
// WAR deps (RD0 overwrites [*][0] read by octet1) keep intra-region order.
#define REGION(QM, QN, RD0, RD1, STAGE, WAITV) do {                            \
  __builtin_amdgcn_s_barrier();                                                \
  WAITV;                                                                       \
  SB0;                                                                         \
  __builtin_amdgcn_s_setprio(1);                                               \
  STAGE;                                                                       \
  MFMA_KK(QM, QN, 0);                                                          \
  RD0;                                                                         \
  SB0;                                                                         \
  MFMA_KK(QM, QN, 1);                                                          \
  RD1;                                                                         \
  SB0;                                                                         \
  __builtin_amdgcn_s_setprio(0);                                               \
} while (0)

__global__ __launch_bounds__(512, 2) void gemm_kernel(
    const unsigned short* __restrict__ Ag,   // Xb [M][K] bf16
    const unsigned short* __restrict__ Bg,   // Wb [N][K] bf16
    const float* __restrict__ bias,
    float* __restrict__ C) {
  __shared__ __align__(16) char smem[131072];   // A: [0,64K), B: [64K,128K)

  // XCD-aware bijective swizzle: 512 blocks % 8 == 0
  int bid = blockIdx.x;
  int cpx = gridDim.x >> 3;
  int swz = (bid & 7) * cpx + (bid >> 3);
  int tm = swz >> 4;                 // 32 M-tiles
  int tn = swz & 15;                 // 16 N-tiles
  int m0 = tm * BM, n0 = tn * BN;

  int tid = threadIdx.x;
  int lane = tid & 63;
  int wid = tid >> 6;                // 8 waves
  int wr = wid >> 2, wc = wid & 3;   // 2 x 4

  // hoisted lane addressing (R4, validated)
  const int xorv = (lane & 7) << 4;
  const int hi4 = (lane >> 4) << 4;
  const int wrbase = wr * 64 + (lane & 15);
  const int wcbase = wc * 32 + (lane & 15);
  const int a_off0 = (wrbase << 7) + (hi4 ^ xorv);
  const int a_off1 = (wrbase << 7) + ((64 | hi4) ^ xorv);
  const int b_off0 = 65536 + (wcbase << 7) + (hi4 ^ xorv);
  const int b_off1 = 65536 + (wcbase << 7) + ((64 | hi4) ^ xorv);
  const int wslot = (tid >> 6) << 10;
  const int s_lr0 = tid >> 3, s_lr1 = 64 + (tid >> 3);
  const int s_off0 = s_lr0 * K_DIM + (((tid & 7) ^ (s_lr0 & 7)) << 3);
  const int s_off1 = s_lr1 * K_DIM + (((tid & 7) ^ (s_lr1 & 7)) << 3);

  short8 a_[4][2], b_[2][2];
  f32x4 acc[2][2][4][2];
#pragma unroll
  for (int i = 0; i < 2; ++i)
#pragma unroll
    for (int j = 0; j < 2; ++j)
#pragma unroll
      for (int mf = 0; mf < 4; ++mf)
#pragma unroll
        for (int nf = 0; nf < 2; ++nf) acc[i][j][mf][nf] = (f32x4){0.f, 0.f, 0.f, 0.f};

  // prologue: buf0 <- kt0 (B00,A00,B01,A01), buf1 A10 <- kt1.
  // vmcnt(2): ALL buf0 loads landed; barrier; then cross-slot ds_reads.
  STG_B(0, 0, 0); STG_A(0, 0, 0); STG_B(0, 1, 0); STG_A(0, 1, 0);
  STG_A(1, 0, 1);
  VMCNT2;
  __builtin_amdgcn_s_barrier();
  LA(0, 0, 0); LB(0, 0, 0); LA(0, 0, 1); LB(0, 0, 1);  // reads for region 1

  for (int t = 0; t < 31; ++t) {
    const int kt1 = 2 * t + 1;     // buf0 = kt1-1, buf1 = kt1
    REGION(0, 0, LB(0,1,0),            LB(0,1,1),            STG_B(1,0,kt1),   VMCNT2);
    REGION(0, 1, LA(0,1,0),            LA(0,1,1),            STG_B(1,1,kt1),   VMCNT2);
    REGION(1, 1, LB(0,0,0),            LB(0,0,1),            STG_A(1,1,kt1),   VMCNT2);
    REGION(1, 0, LA(1,0,0); LB(1,0,0), LA(1,0,1); LB(1,0,1), STG_B(0,0,kt1+1), VMCNT2);
    REGION(0, 0, LB(1,1,0),            LB(1,1,1),            STG_A(0,0,kt1+1), VMCNT2);
    REGION(0, 1, LA(1,1,0),            LA(1,1,1),            STG_B(0,1,kt1+1), VMCNT2);
    REGION(1, 1, LB(1,0,0),            LB(1,0,1),            STG_A(0,1,kt1+1), VMCNT2);
    REGION(1, 0, LA(0,0,0); LB(0,0,0), LA(0,0,1); LB(0,0,1), STG_A(1,0,kt1+2), VMCNT2);
  }
  // peeled final iteration: buf0 = 62, buf1 = 63; no OOB stages.
  // Drain of A11(63) pulled to p5 (vmcnt(0)) so p6's read is barrier-separated.
  REGION(0, 0, LB(0,1,0),            LB(0,1,1),            STG_B(1,0,63), VMCNT2);
  REGION(0, 1, LA(0,1,0),            LA(0,1,1),            STG_B(1,1,63), VMCNT2);
  REGION(1, 1, LB(0,0,0),            LB(0,0,1),            STG_A(1,1,63), VMCNT2);
  REGION(1, 0, LA(1,0,0); LB(1,0,0), LA(1,0,1); LB(1,0,1), NOOP,          VMCNT2);
  REGION(0, 0, LB(1,1,0),            LB(1,1,1),            NOOP,          VMCNT0);
  REGION(0, 1, LA(1,1,0),            LA(1,1,1),            NOOP,          NOOP);
  REGION(1, 1, LB(1,0,0),            LB(1,0,1),            NOOP,          NOOP);
  REGION(1, 0, NOOP,                 NOOP,                 NOOP,          NOOP);

  // epilogue: C/D layout col=lane&15, row=(lane>>4)*4+j
#pragma unroll
  for (int qn = 0; qn < 2; ++qn)
#pragma unroll
    for (int nf = 0; nf < 2; ++nf) {
      int gcol = n0 + qn * 128 + wc * 32 + nf * 16 + (lane & 15);
      float bv = bias[gcol];
#pragma unroll
      for (int qm = 0; qm < 2; ++qm)
#pragma unroll
        for (int mf = 0; mf < 4; ++mf) {
          int grow = m0 + qm * 128 + wr * 64 + mf * 16 + ((lane >> 4) << 2);
          f32x4 v = acc[qm][qn][mf][nf];
#pragma unroll
          for (int j = 0; j < 4; ++j)
            C[(size_t)(grow + j) * N_DIM + gcol] = v[j] + bv;
        }
    }
}

extern "C" void kernel_launch(void* const* d_in, const int* in_sizes, int n_in,
                              void* d_out, int out_size, void* d_ws, size_t ws_size,
                              hipStream_t stream) {
  const float* x       = (const float*)d_in[0];
  const int*   qweight = (const int*)d_in[1];
  const float* scale   = (const float*)d_in[2];
  const float* zero    = (const float*)d_in[3];
  const float* bias    = (const float*)d_in[4];
  float* out = (float*)d_out;

  unsigned short* Xb = (unsigned short*)d_ws;                    // 64 MB
  unsigned short* Wb = Xb + (size_t)M_DIM * K_DIM;               // 32 MB

  prep_kernel<<<16384 + 2048, 256, 0, stream>>>(x, Xb, qweight, scale, zero, Wb);
  gemm_kernel<<<(M_DIM / BM) * (N_DIM / BN), 512, 0, stream>>>(Xb, Wb, bias, out);
}